// Round 13
// baseline (286.590 us; speedup 1.0000x reference)
//
#include <hip/hip_runtime.h>
#include <hip/hip_fp16.h>
#include <math.h>

#define NEG_SLOPE 0.2f
#define TILE 8192
// assumes NB = ceil(N/256) <= 512 (N <= 131072)

__device__ __forceinline__ float wave_reduce_sum(float v){
  #pragma unroll
  for (int off = 32; off > 0; off >>= 1) v += __shfl_xor(v, off, 64);
  return v;
}
__device__ __forceinline__ float wave_reduce_max(float v){
  #pragma unroll
  for (int off = 32; off > 0; off >>= 1) v = fmaxf(v, __shfl_xor(v, off, 64));
  return v;
}

// ---------------- CSR build (bucketed) ----------------

__global__ void k_bcount(const int* __restrict__ ei, int* __restrict__ C,
                         int* __restrict__ Btot, int E, int TOT, int NB, int T){
  __shared__ int hist[512];
  int t = blockIdx.x;
  for (int i = threadIdx.x; i < NB; i += blockDim.x) hist[i] = 0;
  __syncthreads();
  int base = t * TILE;
  for (int k = threadIdx.x; k < TILE; k += blockDim.x){
    int j = base + k;
    if (j < TOT){
      int d = (j < E) ? ei[E + j] : (j - E);
      atomicAdd(&hist[d >> 8], 1);
    }
  }
  __syncthreads();
  for (int b = threadIdx.x; b < NB; b += blockDim.x){
    int v = hist[b];
    C[(size_t)b * T + t] = v;
    if (v) atomicAdd(&Btot[b], v);
  }
}

__global__ void k_bstart(const int* __restrict__ Btot, int* __restrict__ Bstart,
                         int* __restrict__ rowptr, int NB, int TOT, int N){
  __shared__ int lds[512];
  int t = threadIdx.x;
  int total = (t < NB) ? Btot[t] : 0;
  lds[t] = total; __syncthreads();
  for (int off = 1; off < 512; off <<= 1){
    int x = (t >= off) ? lds[t - off] : 0;
    __syncthreads();
    lds[t] += x;
    __syncthreads();
  }
  if (t < NB) Bstart[t] = lds[t] - total;   // exclusive
  if (t == 0){ Bstart[NB] = TOT; rowptr[N] = TOT; }
}

__global__ void k_bcolscan(const int* __restrict__ C, const int* __restrict__ Bstart,
                           int* __restrict__ O, int NB, int T){
  int wid = (blockIdx.x * blockDim.x + threadIdx.x) >> 6;
  int lane = threadIdx.x & 63;
  if (wid >= NB) return;
  int run = Bstart[wid];
  int nchunks = (T + 63) / 64;
  for (int i = 0; i < nchunks; i++){
    int t = i * 64 + lane;
    int v = (t < T) ? C[(size_t)wid * T + t] : 0;
    int s = v;
    #pragma unroll
    for (int off = 1; off < 64; off <<= 1){
      int u = __shfl_up(s, off);
      if (lane >= off) s += u;
    }
    if (t < T) O[(size_t)wid * T + t] = run + (s - v);
    run += __shfl(s, 63);
  }
}

__global__ void k_bscatter(const int* __restrict__ ei, const int* __restrict__ O,
                           unsigned int* __restrict__ tmp, int E, int TOT, int NB, int T){
  __shared__ int cur[512];
  int t = blockIdx.x;
  for (int b = threadIdx.x; b < NB; b += blockDim.x) cur[b] = O[(size_t)b * T + t];
  __syncthreads();
  int base = t * TILE;
  for (int k = threadIdx.x; k < TILE; k += blockDim.x){
    int j = base + k;
    if (j < TOT){
      int s, d;
      if (j < E){ s = ei[j]; d = ei[E + j]; } else { s = j - E; d = s; }
      int r = atomicAdd(&cur[d >> 8], 1);
      tmp[r] = ((unsigned)s << 8) | (unsigned)(d & 255);
    }
  }
}

__global__ void k_bfinal(const unsigned int* __restrict__ tmp, const int* __restrict__ Bstart,
                         int* __restrict__ rowptr, int* __restrict__ col, int N){
  __shared__ int hist[256];
  __shared__ int sc[256];
  __shared__ int cur[256];
  int b = blockIdx.x;
  int base_node = b << 8;
  int nnode = min(256, N - base_node);
  int beg = Bstart[b], end = Bstart[b + 1];
  int t = threadIdx.x;
  if (t < 256) hist[t] = 0;
  __syncthreads();
  for (int j = beg + t; j < end; j += blockDim.x)
    atomicAdd(&hist[tmp[j] & 255u], 1);
  __syncthreads();
  int v = 0;
  if (t < 256){ v = hist[t]; sc[t] = v; }
  __syncthreads();
  for (int off = 1; off < 256; off <<= 1){
    int x = (t < 256 && t >= off) ? sc[t - off] : 0;
    __syncthreads();
    if (t < 256) sc[t] += x;
    __syncthreads();
  }
  if (t < 256){
    int excl = sc[t] - v;
    if (t < nnode) rowptr[base_node + t] = beg + excl;
    cur[t] = beg + excl;
  }
  __syncthreads();
  for (int j = beg + t; j < end; j += blockDim.x){
    unsigned u = tmp[j];
    int pos = atomicAdd(&cur[u & 255u], 1);
    col[pos] = (int)(u >> 8);
  }
}

// ---------------- dense layer 1 (register-blocked; h output in fp16) ----------------

__global__ void k_dense16(const float* __restrict__ x, const float* __restrict__ W,
                          const float* __restrict__ asrc, const float* __restrict__ adst,
                          __half* __restrict__ h16, float* __restrict__ sarr, float* __restrict__ darr,
                          int n){
  __shared__ float4 Ws4[16 * 16];
  __shared__ float as_s[64], ad_s[64];
  int t = threadIdx.x;
  const float4* W4 = (const float4*)W;
  if (t < 16 * 16) Ws4[t] = W4[t];
  if (t < 64){ as_s[t] = asrc[t]; ad_s[t] = adst[t]; }
  __syncthreads();
  int gid = blockIdx.x * blockDim.x + t;
  int node = gid >> 1;
  int half = gid & 1;
  if (node >= n) return;
  const float4* xr = (const float4*)(x + (size_t)node * 16);
  float4 acc[8] = {};
  #pragma unroll
  for (int kk = 0; kk < 4; kk++){
    float4 xv = xr[kk];
    #pragma unroll
    for (int i = 0; i < 4; i++){
      float xk = (i == 0) ? xv.x : (i == 1) ? xv.y : (i == 2) ? xv.z : xv.w;
      const float4* wrow = &Ws4[(kk * 4 + i) * 16 + half * 8];
      #pragma unroll
      for (int c = 0; c < 8; c++){
        acc[c].x = fmaf(xk, wrow[c].x, acc[c].x);
        acc[c].y = fmaf(xk, wrow[c].y, acc[c].y);
        acc[c].z = fmaf(xk, wrow[c].z, acc[c].z);
        acc[c].w = fmaf(xk, wrow[c].w, acc[c].w);
      }
    }
  }
  float sv = 0.f, dv = 0.f;
  #pragma unroll
  for (int c = 0; c < 8; c += 2){
    union { __half2 h2[4]; uint4 u; } pk;
    pk.h2[0] = __floats2half2_rn(acc[c].x,   acc[c].y);
    pk.h2[1] = __floats2half2_rn(acc[c].z,   acc[c].w);
    pk.h2[2] = __floats2half2_rn(acc[c+1].x, acc[c+1].y);
    pk.h2[3] = __floats2half2_rn(acc[c+1].z, acc[c+1].w);
    *(uint4*)(h16 + (size_t)node * 64 + half * 32 + c * 4) = pk.u;
  }
  #pragma unroll
  for (int c = 0; c < 8; c++){
    int cb = half * 32 + c * 4;
    sv += acc[c].x * as_s[cb] + acc[c].y * as_s[cb+1] + acc[c].z * as_s[cb+2] + acc[c].w * as_s[cb+3];
    dv += acc[c].x * ad_s[cb] + acc[c].y * ad_s[cb+1] + acc[c].z * ad_s[cb+2] + acc[c].w * ad_s[cb+3];
  }
  sv += __shfl_xor(sv, 1);
  dv += __shfl_xor(dv, 1);
  if (half == 0){ sarr[node] = sv; darr[node] = dv; }
}

// ---------------- GAT softmax-aggregate helpers ----------------

__device__ __forceinline__ void agg_softmax(const float* sarr, const int* col,
                                            int beg, int deg, float dn, int lane,
                                            int& c0, int& c1, float& a0, float& a1){
  c0 = 0; c1 = 0;
  float e0 = -INFINITY, e1 = -INFINITY;
  if (lane < deg){
    c0 = col[beg + lane];
    float t = sarr[c0] + dn;
    e0 = (t > 0.f) ? t : NEG_SLOPE * t;
  }
  if (lane + 64 < deg){
    c1 = col[beg + lane + 64];
    float t = sarr[c1] + dn;
    e1 = (t > 0.f) ? t : NEG_SLOPE * t;
  }
  float m = wave_reduce_max(fmaxf(e0, e1));
  float w0 = (lane < deg)      ? __expf(e0 - m) : 0.f;
  float w1 = (lane + 64 < deg) ? __expf(e1 - m) : 0.f;
  float sum = wave_reduce_sum(w0 + w1);
  float inv = 1.f / (sum + 1e-16f);
  a0 = w0 * inv; a1 = w1 * inv;
}

// 8 edge-groups (eg = lane&7) x 8 channel-octs (co = lane>>3); 16B loads.
// After the xor-1/2/4 butterfly EVERY lane holds the reduced 8 channels of its oct.
__device__ __forceinline__ void agg_gather16(const __half* h16, int deg, int lane,
                                             const int2* stash, float4& A0, float4& A1){
  int eg = lane & 7, co = lane >> 3;
  float4 a0v = make_float4(0.f,0.f,0.f,0.f), a1v = make_float4(0.f,0.f,0.f,0.f);
  #pragma unroll 2
  for (int j0 = 0; j0 < deg; j0 += 8){
    int idx = j0 + eg;
    if (idx < deg){
      int2 ca = stash[idx];
      float a = __int_as_float(ca.y);
      uint4 raw = *(const uint4*)(h16 + (size_t)ca.x * 64 + co * 8);
      float2 f0 = __half22float2(*(__half2*)&raw.x);
      float2 f1 = __half22float2(*(__half2*)&raw.y);
      float2 f2 = __half22float2(*(__half2*)&raw.z);
      float2 f3 = __half22float2(*(__half2*)&raw.w);
      a0v.x = fmaf(a, f0.x, a0v.x); a0v.y = fmaf(a, f0.y, a0v.y);
      a0v.z = fmaf(a, f1.x, a0v.z); a0v.w = fmaf(a, f1.y, a0v.w);
      a1v.x = fmaf(a, f2.x, a1v.x); a1v.y = fmaf(a, f2.y, a1v.y);
      a1v.z = fmaf(a, f3.x, a1v.z); a1v.w = fmaf(a, f3.y, a1v.w);
    }
  }
  #pragma unroll
  for (int off = 1; off < 8; off <<= 1){
    a0v.x += __shfl_xor(a0v.x, off); a0v.y += __shfl_xor(a0v.y, off);
    a0v.z += __shfl_xor(a0v.z, off); a0v.w += __shfl_xor(a0v.w, off);
    a1v.x += __shfl_xor(a1v.x, off); a1v.y += __shfl_xor(a1v.y, off);
    a1v.z += __shfl_xor(a1v.z, off); a1v.w += __shfl_xor(a1v.w, off);
  }
  A0 = a0v; A1 = a1v;
}

// ---------------- fused layer-1 aggregate + layer-2 dense ----------------
// r = relu(agg1 + b1) in-wave; h2 = r @ W2 via LDS GEMV; writes g16, sB, dB.
// Fixed grid + per-wave node-stride loop so W2 staging is amortized.
__global__ void k_agg1f(const __half* __restrict__ h16, const float* __restrict__ sarr,
                        const float* __restrict__ darr, const int* __restrict__ rowptr,
                        const int* __restrict__ col, const float* __restrict__ b1,
                        const float* __restrict__ W2, const float* __restrict__ as2,
                        const float* __restrict__ ad2,
                        __half* __restrict__ g16, float* __restrict__ sB, float* __restrict__ dB,
                        int n){
  __shared__ int2 stash[4][128];
  __shared__ float W2s[64 * 64];   // transposed: W2s[c'][c] = W2[c][c']
  __shared__ float as_s[64], ad_s[64];
  int t = threadIdx.x;
  for (int i = t; i < 4096; i += 256)
    W2s[(i & 63) * 64 + (i >> 6)] = W2[i];
  if (t < 64){ as_s[t] = as2[t]; ad_s[t] = ad2[t]; }
  __syncthreads();

  int w = t >> 6, lane = t & 63;
  int eg = lane & 7, co = lane >> 3;
  int stride = gridDim.x * 4;

  for (int node = blockIdx.x * 4 + w; node < n; node += stride){
    int beg = rowptr[node];
    int deg = rowptr[node + 1] - beg;
    float dn = darr[node];
    float r[8];

    if (deg <= 128){
      int c0, c1; float a0, a1;
      agg_softmax(sarr, col, beg, deg, dn, lane, c0, c1, a0, a1);
      if (lane < deg)      stash[w][lane]      = make_int2(c0, __float_as_int(a0));
      if (lane + 64 < deg) stash[w][lane + 64] = make_int2(c1, __float_as_int(a1));
      float4 A0, A1;
      agg_gather16(h16, deg, lane, stash[w], A0, A1);
      const float4 b0 = *(const float4*)(b1 + co * 8);
      const float4 b1v = *(const float4*)(b1 + co * 8 + 4);
      r[0] = fmaxf(A0.x + b0.x, 0.f);  r[1] = fmaxf(A0.y + b0.y, 0.f);
      r[2] = fmaxf(A0.z + b0.z, 0.f);  r[3] = fmaxf(A0.w + b0.w, 0.f);
      r[4] = fmaxf(A1.x + b1v.x, 0.f); r[5] = fmaxf(A1.y + b1v.y, 0.f);
      r[6] = fmaxf(A1.z + b1v.z, 0.f); r[7] = fmaxf(A1.w + b1v.w, 0.f);
    } else {
      int end = beg + deg;
      float m = -INFINITY;
      for (int j = beg + lane; j < end; j += 64){
        float e = sarr[col[j]] + dn;
        e = (e > 0.f) ? e : NEG_SLOPE * e;
        m = fmaxf(m, e);
      }
      m = wave_reduce_max(m);
      float sum = 0.f;
      for (int j = beg + lane; j < end; j += 64){
        float e = sarr[col[j]] + dn;
        e = (e > 0.f) ? e : NEG_SLOPE * e;
        sum += __expf(e - m);
      }
      sum = wave_reduce_sum(sum);
      float invden = 1.0f / (sum + 1e-16f);
      float acc = 0.f;
      for (int j = beg; j < end; j++){
        int s = col[j];
        float e = sarr[s] + dn;
        e = (e > 0.f) ? e : NEG_SLOPE * e;
        float alpha = __expf(e - m) * invden;
        acc = fmaf(alpha, __half2float(h16[(size_t)s * 64 + lane]), acc);
      }
      float rs = fmaxf(acc + b1[lane], 0.f);    // channel = lane
      #pragma unroll
      for (int i = 0; i < 8; i++) r[i] = __shfl(rs, co * 8 + i);
    }

    // GEMV: po[j] = sum_i r[i] * W2[co*8+i][eg*8+j], then reduce over co
    float po[8];
    #pragma unroll
    for (int j = 0; j < 8; j++){
      const float4* row = (const float4*)(W2s + (eg * 8 + j) * 64 + co * 8);
      float4 wa = row[0], wb = row[1];
      po[j] = r[0]*wa.x + r[1]*wa.y + r[2]*wa.z + r[3]*wa.w
            + r[4]*wb.x + r[5]*wb.y + r[6]*wb.z + r[7]*wb.w;
    }
    #pragma unroll
    for (int off = 8; off < 64; off <<= 1){
      #pragma unroll
      for (int j = 0; j < 8; j++) po[j] += __shfl_xor(po[j], off);
    }
    // write g16 row (lanes with co==0 cover 8 octs of 8 channels)
    if (co == 0){
      union { __half2 h2[4]; uint4 u; } pk;
      pk.h2[0] = __floats2half2_rn(po[0], po[1]);
      pk.h2[1] = __floats2half2_rn(po[2], po[3]);
      pk.h2[2] = __floats2half2_rn(po[4], po[5]);
      pk.h2[3] = __floats2half2_rn(po[6], po[7]);
      *(uint4*)(g16 + (size_t)node * 64 + eg * 8) = pk.u;
    }
    // s,d dots: partial over this lane's 8 output channels (eg*8..eg*8+7)
    float sv = 0.f, dv = 0.f;
    #pragma unroll
    for (int j = 0; j < 8; j++){
      sv += po[j] * as_s[eg * 8 + j];
      dv += po[j] * ad_s[eg * 8 + j];
    }
    sv += __shfl_xor(sv, 1); sv += __shfl_xor(sv, 2); sv += __shfl_xor(sv, 4);
    dv += __shfl_xor(dv, 1); dv += __shfl_xor(dv, 2); dv += __shfl_xor(dv, 4);
    if (lane == 0){ sB[node] = sv; dB[node] = dv; }
  }
}

// layer-2 aggregate + fused policy head: writes [N][8] fp32.
__global__ void k_agg2(const __half* __restrict__ h16, const float* __restrict__ sarr,
                       const float* __restrict__ darr, const int* __restrict__ rowptr,
                       const int* __restrict__ col, const float* __restrict__ bias,
                       const float* __restrict__ Wp, const float* __restrict__ bp,
                       float* __restrict__ out, int n){
  __shared__ int2 stash[4][128];
  int w = threadIdx.x >> 6;
  int lane = threadIdx.x & 63;
  int o = lane & 7, g = lane >> 3;
  float wp[8];
  #pragma unroll
  for (int j = 0; j < 8; j++) wp[j] = Wp[(g * 8 + j) * 8 + o];
  float bpv = bp[o];

  int node = blockIdx.x * (blockDim.x >> 6) + w;
  if (node >= n) return;
  int beg = rowptr[node];
  int deg = rowptr[node + 1] - beg;
  float dn = darr[node];

  if (deg <= 128){
    int c0, c1; float a0, a1;
    agg_softmax(sarr, col, beg, deg, dn, lane, c0, c1, a0, a1);
    if (lane < deg)      stash[w][lane]      = make_int2(c0, __float_as_int(a0));
    if (lane + 64 < deg) stash[w][lane + 64] = make_int2(c1, __float_as_int(a1));
    float4 A0, A1;
    agg_gather16(h16, deg, lane, stash[w], A0, A1);
    const float4 b0 = *(const float4*)(bias + g * 8);
    const float4 b1 = *(const float4*)(bias + g * 8 + 4);
    float r0 = fmaxf(A0.x + b0.x, 0.f), r1 = fmaxf(A0.y + b0.y, 0.f);
    float r2 = fmaxf(A0.z + b0.z, 0.f), r3 = fmaxf(A0.w + b0.w, 0.f);
    float r4 = fmaxf(A1.x + b1.x, 0.f), r5 = fmaxf(A1.y + b1.y, 0.f);
    float r6 = fmaxf(A1.z + b1.z, 0.f), r7 = fmaxf(A1.w + b1.w, 0.f);
    float po = r0*wp[0] + r1*wp[1] + r2*wp[2] + r3*wp[3]
             + r4*wp[4] + r5*wp[5] + r6*wp[6] + r7*wp[7];
    po += __shfl_xor(po, 8);
    po += __shfl_xor(po, 16);
    po += __shfl_xor(po, 32);
    if (lane < 8) out[(size_t)node * 8 + lane] = po + bpv;
  } else {
    int end = beg + deg;
    float m = -INFINITY;
    for (int j = beg + lane; j < end; j += 64){
      float e = sarr[col[j]] + dn;
      e = (e > 0.f) ? e : NEG_SLOPE * e;
      m = fmaxf(m, e);
    }
    m = wave_reduce_max(m);
    float sum = 0.f;
    for (int j = beg + lane; j < end; j += 64){
      float e = sarr[col[j]] + dn;
      e = (e > 0.f) ? e : NEG_SLOPE * e;
      sum += __expf(e - m);
    }
    sum = wave_reduce_sum(sum);
    float invden = 1.0f / (sum + 1e-16f);
    float acc = 0.f;
    for (int j = beg; j < end; j++){
      int s = col[j];
      float e = sarr[s] + dn;
      e = (e > 0.f) ? e : NEG_SLOPE * e;
      float alpha = __expf(e - m) * invden;
      acc = fmaf(alpha, __half2float(h16[(size_t)s * 64 + lane]), acc);
    }
    float r = fmaxf(acc + bias[lane], 0.f);   // channel = lane
    float po = 0.f;
    #pragma unroll
    for (int j = 0; j < 8; j++) po += __shfl(r, g * 8 + j) * wp[j];
    po += __shfl_xor(po, 8);
    po += __shfl_xor(po, 16);
    po += __shfl_xor(po, 32);
    if (lane < 8) out[(size_t)node * 8 + lane] = po + bpv;
  }
}

// ---------------- launch ----------------

extern "C" void kernel_launch(void* const* d_in, const int* in_sizes, int n_in,
                              void* d_out, int out_size, void* d_ws, size_t ws_size,
                              hipStream_t stream) {
  const float* x   = (const float*)d_in[0];
  const int*   ei  = (const int*)  d_in[1];
  const float* W1  = (const float*)d_in[2];
  const float* as1 = (const float*)d_in[3];
  const float* ad1 = (const float*)d_in[4];
  const float* b1  = (const float*)d_in[5];
  const float* W2  = (const float*)d_in[6];
  const float* as2 = (const float*)d_in[7];
  const float* ad2 = (const float*)d_in[8];
  const float* b2  = (const float*)d_in[9];
  const float* Wp  = (const float*)d_in[10];
  const float* bp  = (const float*)d_in[11];
  float* out = (float*)d_out;

  int N = in_sizes[0] / 16;
  int E = in_sizes[1] / 2;
  int TOT = E + N;
  int NB = (N + 255) >> 8;            // buckets of 256 dst nodes
  int T  = (TOT + TILE - 1) / TILE;   // edge tiles

  char* p = (char*)d_ws;
  auto alloc = [&](size_t bytes) -> char* {
    char* r = p; p += (bytes + 255) & ~(size_t)255; return r;
  };
  __half* h16   = (__half*)alloc((size_t)N * 64 * 2);   // layer-1 h table
  __half* g16   = (__half*)alloc((size_t)N * 64 * 2);   // layer-2 h table
  float* sA     = (float*)alloc((size_t)N * 4);
  float* dA     = (float*)alloc((size_t)N * 4);
  float* sB     = (float*)alloc((size_t)N * 4);
  float* dB     = (float*)alloc((size_t)N * 4);
  int*   rowptr = (int*)  alloc((size_t)(N + 1) * 4);
  int*   col    = (int*)  alloc((size_t)TOT * 4);
  int*   Bstart = (int*)  alloc((size_t)(NB + 1) * 4);
  int*   Btot   = (int*)  alloc((size_t)(NB + 1) * 4);

  // scratch aliased onto h16/g16 (both first written AFTER the CSR build)
  unsigned int* tmp  = (unsigned int*)h16;         // TOT u32 <= N*64*2
  int*          Cmat = (int*)g16;                  // NB*T ints (~325KB)
  int*          Omat = Cmat + (size_t)NB * T;      // NB*T ints

  const int tb = 256;

  // CSR build (dst-grouped) — bucket pipeline
  (void)hipMemsetAsync(Btot, 0, (size_t)(NB + 1) * 4, stream);
  k_bcount<<<T, tb, 0, stream>>>(ei, Cmat, Btot, E, TOT, NB, T);
  k_bstart<<<1, 512, 0, stream>>>(Btot, Bstart, rowptr, NB, TOT, N);
  k_bcolscan<<<(NB + 3) / 4, tb, 0, stream>>>(Cmat, Bstart, Omat, NB, T);
  k_bscatter<<<T, tb, 0, stream>>>(ei, Omat, tmp, E, TOT, NB, T);
  k_bfinal<<<NB, 512, 0, stream>>>(tmp, Bstart, rowptr, col, N);

  // layer 1 dense
  k_dense16<<<(2 * N + tb - 1) / tb, tb, 0, stream>>>(x, W1, as1, ad1, h16, sA, dA, N);
  // fused: layer-1 aggregate + layer-2 dense (fixed grid, node-stride loop)
  int g1blocks = 2048;
  k_agg1f<<<g1blocks, 256, 0, stream>>>(h16, sA, dA, rowptr, col, b1,
                                        W2, as2, ad2, g16, sB, dB, N);
  // layer-2 aggregate + fused policy head
  k_agg2<<<(N + 3) / 4, 256, 0, stream>>>(g16, sB, dB, rowptr, col, b2, Wp, bp, out, N);
}

// Round 14
// 214.980 us; speedup vs baseline: 1.3331x; 1.3331x over previous
//
#include <hip/hip_runtime.h>
#include <hip/hip_fp16.h>
#include <math.h>

#define NEG_SLOPE 0.2f
#define TILE 8192
// assumes NB = ceil(N/256) <= 512 (N <= 131072)

__device__ __forceinline__ float wave_reduce_sum(float v){
  #pragma unroll
  for (int off = 32; off > 0; off >>= 1) v += __shfl_xor(v, off, 64);
  return v;
}
__device__ __forceinline__ float wave_reduce_max(float v){
  #pragma unroll
  for (int off = 32; off > 0; off >>= 1) v = fmaxf(v, __shfl_xor(v, off, 64));
  return v;
}

// ---------------- CSR build (bucketed) ----------------

__global__ void k_bcount(const int* __restrict__ ei, int* __restrict__ C,
                         int* __restrict__ Btot, int E, int TOT, int NB, int T){
  __shared__ int hist[512];
  int t = blockIdx.x;
  for (int i = threadIdx.x; i < NB; i += blockDim.x) hist[i] = 0;
  __syncthreads();
  int base = t * TILE;
  for (int k = threadIdx.x; k < TILE; k += blockDim.x){
    int j = base + k;
    if (j < TOT){
      int d = (j < E) ? ei[E + j] : (j - E);
      atomicAdd(&hist[d >> 8], 1);
    }
  }
  __syncthreads();
  for (int b = threadIdx.x; b < NB; b += blockDim.x){
    int v = hist[b];
    C[(size_t)b * T + t] = v;
    if (v) atomicAdd(&Btot[b], v);
  }
}

__global__ void k_bstart(const int* __restrict__ Btot, int* __restrict__ Bstart,
                         int* __restrict__ rowptr, int NB, int TOT, int N){
  __shared__ int lds[512];
  int t = threadIdx.x;
  int total = (t < NB) ? Btot[t] : 0;
  lds[t] = total; __syncthreads();
  for (int off = 1; off < 512; off <<= 1){
    int x = (t >= off) ? lds[t - off] : 0;
    __syncthreads();
    lds[t] += x;
    __syncthreads();
  }
  if (t < NB) Bstart[t] = lds[t] - total;   // exclusive
  if (t == 0){ Bstart[NB] = TOT; rowptr[N] = TOT; }
}

__global__ void k_bcolscan(const int* __restrict__ C, const int* __restrict__ Bstart,
                           int* __restrict__ O, int NB, int T){
  int wid = (blockIdx.x * blockDim.x + threadIdx.x) >> 6;
  int lane = threadIdx.x & 63;
  if (wid >= NB) return;
  int run = Bstart[wid];
  int nchunks = (T + 63) / 64;
  for (int i = 0; i < nchunks; i++){
    int t = i * 64 + lane;
    int v = (t < T) ? C[(size_t)wid * T + t] : 0;
    int s = v;
    #pragma unroll
    for (int off = 1; off < 64; off <<= 1){
      int u = __shfl_up(s, off);
      if (lane >= off) s += u;
    }
    if (t < T) O[(size_t)wid * T + t] = run + (s - v);
    run += __shfl(s, 63);
  }
}

__global__ void k_bscatter(const int* __restrict__ ei, const int* __restrict__ O,
                           unsigned int* __restrict__ tmp, int E, int TOT, int NB, int T){
  __shared__ int cur[512];
  int t = blockIdx.x;
  for (int b = threadIdx.x; b < NB; b += blockDim.x) cur[b] = O[(size_t)b * T + t];
  __syncthreads();
  int base = t * TILE;
  for (int k = threadIdx.x; k < TILE; k += blockDim.x){
    int j = base + k;
    if (j < TOT){
      int s, d;
      if (j < E){ s = ei[j]; d = ei[E + j]; } else { s = j - E; d = s; }
      int r = atomicAdd(&cur[d >> 8], 1);
      tmp[r] = ((unsigned)s << 8) | (unsigned)(d & 255);
    }
  }
}

__global__ void k_bfinal(const unsigned int* __restrict__ tmp, const int* __restrict__ Bstart,
                         int* __restrict__ rowptr, int* __restrict__ col, int N){
  __shared__ int hist[256];
  __shared__ int sc[256];
  __shared__ int cur[256];
  int b = blockIdx.x;
  int base_node = b << 8;
  int nnode = min(256, N - base_node);
  int beg = Bstart[b], end = Bstart[b + 1];
  int t = threadIdx.x;
  hist[t] = 0;
  __syncthreads();
  for (int j = beg + t; j < end; j += blockDim.x)
    atomicAdd(&hist[tmp[j] & 255u], 1);
  __syncthreads();
  int v = hist[t];
  sc[t] = v; __syncthreads();
  for (int off = 1; off < 256; off <<= 1){
    int x = (t >= off) ? sc[t - off] : 0;
    __syncthreads();
    sc[t] += x;
    __syncthreads();
  }
  int excl = sc[t] - v;
  if (t < nnode) rowptr[base_node + t] = beg + excl;
  cur[t] = beg + excl;
  __syncthreads();
  for (int j = beg + t; j < end; j += blockDim.x){
    unsigned u = tmp[j];
    int pos = atomicAdd(&cur[u & 255u], 1);
    col[pos] = (int)(u >> 8);
  }
}

// ---------------- dense ops (register-blocked; h output in fp16) ----------------

__global__ void k_dense16(const float* __restrict__ x, const float* __restrict__ W,
                          const float* __restrict__ asrc, const float* __restrict__ adst,
                          __half* __restrict__ h16, float* __restrict__ sarr, float* __restrict__ darr,
                          int n){
  __shared__ float4 Ws4[16 * 16];
  __shared__ float as_s[64], ad_s[64];
  int t = threadIdx.x;
  const float4* W4 = (const float4*)W;
  if (t < 16 * 16) Ws4[t] = W4[t];
  if (t < 64){ as_s[t] = asrc[t]; ad_s[t] = adst[t]; }
  __syncthreads();
  int gid = blockIdx.x * blockDim.x + t;
  int node = gid >> 1;
  int half = gid & 1;
  if (node >= n) return;
  const float4* xr = (const float4*)(x + (size_t)node * 16);
  float4 acc[8] = {};
  #pragma unroll
  for (int kk = 0; kk < 4; kk++){
    float4 xv = xr[kk];
    #pragma unroll
    for (int i = 0; i < 4; i++){
      float xk = (i == 0) ? xv.x : (i == 1) ? xv.y : (i == 2) ? xv.z : xv.w;
      const float4* wrow = &Ws4[(kk * 4 + i) * 16 + half * 8];
      #pragma unroll
      for (int c = 0; c < 8; c++){
        acc[c].x = fmaf(xk, wrow[c].x, acc[c].x);
        acc[c].y = fmaf(xk, wrow[c].y, acc[c].y);
        acc[c].z = fmaf(xk, wrow[c].z, acc[c].z);
        acc[c].w = fmaf(xk, wrow[c].w, acc[c].w);
      }
    }
  }
  float sv = 0.f, dv = 0.f;
  #pragma unroll
  for (int c = 0; c < 8; c += 2){
    union { __half2 h2[4]; uint4 u; } pk;
    pk.h2[0] = __floats2half2_rn(acc[c].x,   acc[c].y);
    pk.h2[1] = __floats2half2_rn(acc[c].z,   acc[c].w);
    pk.h2[2] = __floats2half2_rn(acc[c+1].x, acc[c+1].y);
    pk.h2[3] = __floats2half2_rn(acc[c+1].z, acc[c+1].w);
    *(uint4*)(h16 + (size_t)node * 64 + half * 32 + c * 4) = pk.u;
  }
  #pragma unroll
  for (int c = 0; c < 8; c++){
    int cb = half * 32 + c * 4;
    sv += acc[c].x * as_s[cb] + acc[c].y * as_s[cb+1] + acc[c].z * as_s[cb+2] + acc[c].w * as_s[cb+3];
    dv += acc[c].x * ad_s[cb] + acc[c].y * ad_s[cb+1] + acc[c].z * ad_s[cb+2] + acc[c].w * ad_s[cb+3];
  }
  sv += __shfl_xor(sv, 1);
  dv += __shfl_xor(dv, 1);
  if (half == 0){ sarr[node] = sv; darr[node] = dv; }
}

__global__ void k_dense64(const float* __restrict__ x, const float* __restrict__ W,
                          const float* __restrict__ asrc, const float* __restrict__ adst,
                          __half* __restrict__ h16, float* __restrict__ sarr, float* __restrict__ darr,
                          int n){
  __shared__ float4 Ws4[64 * 16];   // 16 KB
  __shared__ float as_s[64], ad_s[64];
  int t = threadIdx.x;
  const float4* W4 = (const float4*)W;
  for (int i = t; i < 64 * 16; i += blockDim.x) Ws4[i] = W4[i];
  if (t < 64){ as_s[t] = asrc[t]; ad_s[t] = adst[t]; }
  __syncthreads();
  int gid = blockIdx.x * blockDim.x + t;
  int node = gid >> 1;
  int half = gid & 1;
  if (node >= n) return;
  const float4* xr = (const float4*)(x + (size_t)node * 64);
  float4 acc[8] = {};
  #pragma unroll
  for (int kk = 0; kk < 16; kk++){
    float4 xv = xr[kk];
    #pragma unroll
    for (int i = 0; i < 4; i++){
      float xk = (i == 0) ? xv.x : (i == 1) ? xv.y : (i == 2) ? xv.z : xv.w;
      const float4* wrow = &Ws4[(kk * 4 + i) * 16 + half * 8];
      #pragma unroll
      for (int c = 0; c < 8; c++){
        acc[c].x = fmaf(xk, wrow[c].x, acc[c].x);
        acc[c].y = fmaf(xk, wrow[c].y, acc[c].y);
        acc[c].z = fmaf(xk, wrow[c].z, acc[c].z);
        acc[c].w = fmaf(xk, wrow[c].w, acc[c].w);
      }
    }
  }
  float sv = 0.f, dv = 0.f;
  #pragma unroll
  for (int c = 0; c < 8; c += 2){
    union { __half2 h2[4]; uint4 u; } pk;
    pk.h2[0] = __floats2half2_rn(acc[c].x,   acc[c].y);
    pk.h2[1] = __floats2half2_rn(acc[c].z,   acc[c].w);
    pk.h2[2] = __floats2half2_rn(acc[c+1].x, acc[c+1].y);
    pk.h2[3] = __floats2half2_rn(acc[c+1].z, acc[c+1].w);
    *(uint4*)(h16 + (size_t)node * 64 + half * 32 + c * 4) = pk.u;
  }
  #pragma unroll
  for (int c = 0; c < 8; c++){
    int cb = half * 32 + c * 4;
    sv += acc[c].x * as_s[cb] + acc[c].y * as_s[cb+1] + acc[c].z * as_s[cb+2] + acc[c].w * as_s[cb+3];
    dv += acc[c].x * ad_s[cb] + acc[c].y * ad_s[cb+1] + acc[c].z * ad_s[cb+2] + acc[c].w * ad_s[cb+3];
  }
  sv += __shfl_xor(sv, 1);
  dv += __shfl_xor(dv, 1);
  if (half == 0){ sarr[node] = sv; darr[node] = dv; }
}

// ---------------- GAT softmax-aggregate (2 nodes per wave, fp16 h, LDS stash) ----------------

__device__ __forceinline__ void agg_softmax(const float* sarr, const int* col,
                                            int beg, int deg, float dn, int lane,
                                            int& c0, int& c1, float& a0, float& a1){
  c0 = 0; c1 = 0;
  float e0 = -INFINITY, e1 = -INFINITY;
  if (lane < deg){
    c0 = col[beg + lane];
    float t = sarr[c0] + dn;
    e0 = (t > 0.f) ? t : NEG_SLOPE * t;
  }
  if (lane + 64 < deg){
    c1 = col[beg + lane + 64];
    float t = sarr[c1] + dn;
    e1 = (t > 0.f) ? t : NEG_SLOPE * t;
  }
  float m = wave_reduce_max(fmaxf(e0, e1));
  float w0 = (lane < deg)      ? __expf(e0 - m) : 0.f;
  float w1 = (lane + 64 < deg) ? __expf(e1 - m) : 0.f;
  float sum = wave_reduce_sum(w0 + w1);
  float inv = 1.f / (sum + 1e-16f);
  a0 = w0 * inv; a1 = w1 * inv;
}

// single-node gather (used on fallback path)
__device__ __forceinline__ void agg_gather16(const __half* h16, int deg, int lane,
                                             const int2* stash, float4& A0, float4& A1){
  int eg = lane & 7, co = lane >> 3;
  float4 a0v = make_float4(0.f,0.f,0.f,0.f), a1v = make_float4(0.f,0.f,0.f,0.f);
  #pragma unroll 2
  for (int j0 = 0; j0 < deg; j0 += 8){
    int idx = j0 + eg;
    if (idx < deg){
      int2 ca = stash[idx];
      float a = __int_as_float(ca.y);
      uint4 raw = *(const uint4*)(h16 + (size_t)ca.x * 64 + co * 8);
      float2 f0 = __half22float2(*(__half2*)&raw.x);
      float2 f1 = __half22float2(*(__half2*)&raw.y);
      float2 f2 = __half22float2(*(__half2*)&raw.z);
      float2 f3 = __half22float2(*(__half2*)&raw.w);
      a0v.x = fmaf(a, f0.x, a0v.x); a0v.y = fmaf(a, f0.y, a0v.y);
      a0v.z = fmaf(a, f1.x, a0v.z); a0v.w = fmaf(a, f1.y, a0v.w);
      a1v.x = fmaf(a, f2.x, a1v.x); a1v.y = fmaf(a, f2.y, a1v.y);
      a1v.z = fmaf(a, f3.x, a1v.z); a1v.w = fmaf(a, f3.y, a1v.w);
    }
  }
  #pragma unroll
  for (int off = 1; off < 8; off <<= 1){
    a0v.x += __shfl_xor(a0v.x, off); a0v.y += __shfl_xor(a0v.y, off);
    a0v.z += __shfl_xor(a0v.z, off); a0v.w += __shfl_xor(a0v.w, off);
    a1v.x += __shfl_xor(a1v.x, off); a1v.y += __shfl_xor(a1v.y, off);
    a1v.z += __shfl_xor(a1v.z, off); a1v.w += __shfl_xor(a1v.w, off);
  }
  A0 = a0v; A1 = a1v;
}

// two-node interleaved gather: independent A/B load chains double per-lane MLP
__device__ __forceinline__ void agg_gather16x2(const __half* h16, int degA, int degB,
                                               int lane, const int2* stA, const int2* stB,
                                               float4& A0, float4& A1, float4& B0, float4& B1){
  int eg = lane & 7, co = lane >> 3;
  float4 a0v = make_float4(0.f,0.f,0.f,0.f), a1v = make_float4(0.f,0.f,0.f,0.f);
  float4 b0v = make_float4(0.f,0.f,0.f,0.f), b1v = make_float4(0.f,0.f,0.f,0.f);
  int maxd = max(degA, degB);
  #pragma unroll 2
  for (int j0 = 0; j0 < maxd; j0 += 8){
    int idx = j0 + eg;
    bool okA = idx < degA, okB = idx < degB;
    int2 ca = make_int2(0, 0), cb = make_int2(0, 0);
    if (okA) ca = stA[idx];
    if (okB) cb = stB[idx];
    uint4 rawA = make_uint4(0,0,0,0), rawB = make_uint4(0,0,0,0);
    if (okA) rawA = *(const uint4*)(h16 + (size_t)ca.x * 64 + co * 8);
    if (okB) rawB = *(const uint4*)(h16 + (size_t)cb.x * 64 + co * 8);
    if (okA){
      float a = __int_as_float(ca.y);
      float2 f0 = __half22float2(*(__half2*)&rawA.x);
      float2 f1 = __half22float2(*(__half2*)&rawA.y);
      float2 f2 = __half22float2(*(__half2*)&rawA.z);
      float2 f3 = __half22float2(*(__half2*)&rawA.w);
      a0v.x = fmaf(a, f0.x, a0v.x); a0v.y = fmaf(a, f0.y, a0v.y);
      a0v.z = fmaf(a, f1.x, a0v.z); a0v.w = fmaf(a, f1.y, a0v.w);
      a1v.x = fmaf(a, f2.x, a1v.x); a1v.y = fmaf(a, f2.y, a1v.y);
      a1v.z = fmaf(a, f3.x, a1v.z); a1v.w = fmaf(a, f3.y, a1v.w);
    }
    if (okB){
      float a = __int_as_float(cb.y);
      float2 f0 = __half22float2(*(__half2*)&rawB.x);
      float2 f1 = __half22float2(*(__half2*)&rawB.y);
      float2 f2 = __half22float2(*(__half2*)&rawB.z);
      float2 f3 = __half22float2(*(__half2*)&rawB.w);
      b0v.x = fmaf(a, f0.x, b0v.x); b0v.y = fmaf(a, f0.y, b0v.y);
      b0v.z = fmaf(a, f1.x, b0v.z); b0v.w = fmaf(a, f1.y, b0v.w);
      b1v.x = fmaf(a, f2.x, b1v.x); b1v.y = fmaf(a, f2.y, b1v.y);
      b1v.z = fmaf(a, f3.x, b1v.z); b1v.w = fmaf(a, f3.y, b1v.w);
    }
  }
  #pragma unroll
  for (int off = 1; off < 8; off <<= 1){
    a0v.x += __shfl_xor(a0v.x, off); a0v.y += __shfl_xor(a0v.y, off);
    a0v.z += __shfl_xor(a0v.z, off); a0v.w += __shfl_xor(a0v.w, off);
    a1v.x += __shfl_xor(a1v.x, off); a1v.y += __shfl_xor(a1v.y, off);
    a1v.z += __shfl_xor(a1v.z, off); a1v.w += __shfl_xor(a1v.w, off);
    b0v.x += __shfl_xor(b0v.x, off); b0v.y += __shfl_xor(b0v.y, off);
    b0v.z += __shfl_xor(b0v.z, off); b0v.w += __shfl_xor(b0v.w, off);
    b1v.x += __shfl_xor(b1v.x, off); b1v.y += __shfl_xor(b1v.y, off);
    b1v.z += __shfl_xor(b1v.z, off); b1v.w += __shfl_xor(b1v.w, off);
  }
  A0 = a0v; A1 = a1v; B0 = b0v; B1 = b1v;
}

// slow path (deg>128): lane = channel, serial edges
__device__ __forceinline__ float agg_slow(const __half* h16, const float* sarr,
                                          const int* col, int beg, int deg, float dn, int lane){
  int end = beg + deg;
  float m = -INFINITY;
  for (int j = beg + lane; j < end; j += 64){
    float e = sarr[col[j]] + dn;
    e = (e > 0.f) ? e : NEG_SLOPE * e;
    m = fmaxf(m, e);
  }
  m = wave_reduce_max(m);
  float sum = 0.f;
  for (int j = beg + lane; j < end; j += 64){
    float e = sarr[col[j]] + dn;
    e = (e > 0.f) ? e : NEG_SLOPE * e;
    sum += __expf(e - m);
  }
  sum = wave_reduce_sum(sum);
  float invden = 1.0f / (sum + 1e-16f);
  float acc = 0.f;
  for (int j = beg; j < end; j++){
    int s = col[j];
    float e = sarr[s] + dn;
    e = (e > 0.f) ? e : NEG_SLOPE * e;
    float alpha = __expf(e - m) * invden;
    acc = fmaf(alpha, __half2float(h16[(size_t)s * 64 + lane]), acc);
  }
  return acc;   // channel = lane
}

// layer-1: writes relu(agg + bias) as fp32 [N][64]; 2 nodes per wave
__global__ void k_agg1(const __half* __restrict__ h16, const float* __restrict__ sarr,
                       const float* __restrict__ darr, const int* __restrict__ rowptr,
                       const int* __restrict__ col, const float* __restrict__ bias,
                       float* __restrict__ out, int n){
  __shared__ int2 stash[4][2][128];
  int w = threadIdx.x >> 6;
  int lane = threadIdx.x & 63;
  int eg = lane & 7, co = lane >> 3;
  int nodeA = blockIdx.x * 8 + w * 2;
  int nodeB = nodeA + 1;
  if (nodeA >= n) return;
  bool vB = nodeB < n;

  int begA = rowptr[nodeA], degA = rowptr[nodeA + 1] - begA;
  float dnA = darr[nodeA];
  int begB = 0, degB = 0; float dnB = 0.f;
  if (vB){ begB = rowptr[nodeB]; degB = rowptr[nodeB + 1] - begB; dnB = darr[nodeB]; }
  bool fastA = degA <= 128;
  bool fastB = vB && degB <= 128;

  if (fastA){
    int c0, c1; float a0, a1;
    agg_softmax(sarr, col, begA, degA, dnA, lane, c0, c1, a0, a1);
    if (lane < degA)      stash[w][0][lane]      = make_int2(c0, __float_as_int(a0));
    if (lane + 64 < degA) stash[w][0][lane + 64] = make_int2(c1, __float_as_int(a1));
  }
  if (fastB){
    int c0, c1; float a0, a1;
    agg_softmax(sarr, col, begB, degB, dnB, lane, c0, c1, a0, a1);
    if (lane < degB)      stash[w][1][lane]      = make_int2(c0, __float_as_int(a0));
    if (lane + 64 < degB) stash[w][1][lane + 64] = make_int2(c1, __float_as_int(a1));
  }

  const float4 b0 = *(const float4*)(bias + co * 8);
  const float4 b1 = *(const float4*)(bias + co * 8 + 4);

  if (fastA && fastB){
    float4 A0, A1, B0, B1;
    agg_gather16x2(h16, degA, degB, lane, stash[w][0], stash[w][1], A0, A1, B0, B1);
    if (eg == 0){
      float4 r0, r1;
      r0.x = fmaxf(A0.x + b0.x, 0.f); r0.y = fmaxf(A0.y + b0.y, 0.f);
      r0.z = fmaxf(A0.z + b0.z, 0.f); r0.w = fmaxf(A0.w + b0.w, 0.f);
      r1.x = fmaxf(A1.x + b1.x, 0.f); r1.y = fmaxf(A1.y + b1.y, 0.f);
      r1.z = fmaxf(A1.z + b1.z, 0.f); r1.w = fmaxf(A1.w + b1.w, 0.f);
      *(float4*)(out + (size_t)nodeA * 64 + co * 8)     = r0;
      *(float4*)(out + (size_t)nodeA * 64 + co * 8 + 4) = r1;
      r0.x = fmaxf(B0.x + b0.x, 0.f); r0.y = fmaxf(B0.y + b0.y, 0.f);
      r0.z = fmaxf(B0.z + b0.z, 0.f); r0.w = fmaxf(B0.w + b0.w, 0.f);
      r1.x = fmaxf(B1.x + b1.x, 0.f); r1.y = fmaxf(B1.y + b1.y, 0.f);
      r1.z = fmaxf(B1.z + b1.z, 0.f); r1.w = fmaxf(B1.w + b1.w, 0.f);
      *(float4*)(out + (size_t)nodeB * 64 + co * 8)     = r0;
      *(float4*)(out + (size_t)nodeB * 64 + co * 8 + 4) = r1;
    }
  } else {
    // fallback: handle each node singly
    if (fastA){
      float4 A0, A1;
      agg_gather16(h16, degA, lane, stash[w][0], A0, A1);
      if (eg == 0){
        float4 r0, r1;
        r0.x = fmaxf(A0.x + b0.x, 0.f); r0.y = fmaxf(A0.y + b0.y, 0.f);
        r0.z = fmaxf(A0.z + b0.z, 0.f); r0.w = fmaxf(A0.w + b0.w, 0.f);
        r1.x = fmaxf(A1.x + b1.x, 0.f); r1.y = fmaxf(A1.y + b1.y, 0.f);
        r1.z = fmaxf(A1.z + b1.z, 0.f); r1.w = fmaxf(A1.w + b1.w, 0.f);
        *(float4*)(out + (size_t)nodeA * 64 + co * 8)     = r0;
        *(float4*)(out + (size_t)nodeA * 64 + co * 8 + 4) = r1;
      }
    } else {
      float acc = agg_slow(h16, sarr, col, begA, degA, dnA, lane);
      out[(size_t)nodeA * 64 + lane] = fmaxf(acc + bias[lane], 0.f);
    }
    if (vB){
      if (fastB){
        float4 A0, A1;
        agg_gather16(h16, degB, lane, stash[w][1], A0, A1);
        if (eg == 0){
          float4 r0, r1;
          r0.x = fmaxf(A0.x + b0.x, 0.f); r0.y = fmaxf(A0.y + b0.y, 0.f);
          r0.z = fmaxf(A0.z + b0.z, 0.f); r0.w = fmaxf(A0.w + b0.w, 0.f);
          r1.x = fmaxf(A1.x + b1.x, 0.f); r1.y = fmaxf(A1.y + b1.y, 0.f);
          r1.z = fmaxf(A1.z + b1.z, 0.f); r1.w = fmaxf(A1.w + b1.w, 0.f);
          *(float4*)(out + (size_t)nodeB * 64 + co * 8)     = r0;
          *(float4*)(out + (size_t)nodeB * 64 + co * 8 + 4) = r1;
        }
      } else {
        float acc = agg_slow(h16, sarr, col, begB, degB, dnB, lane);
        out[(size_t)nodeB * 64 + lane] = fmaxf(acc + bias[lane], 0.f);
      }
    }
  }
}

// layer-2 + fused policy head: writes [N][8] fp32; 2 nodes per wave
__global__ void k_agg2(const __half* __restrict__ h16, const float* __restrict__ sarr,
                       const float* __restrict__ darr, const int* __restrict__ rowptr,
                       const int* __restrict__ col, const float* __restrict__ bias,
                       const float* __restrict__ Wp, const float* __restrict__ bp,
                       float* __restrict__ out, int n){
  __shared__ int2 stash[4][2][128];
  int w = threadIdx.x >> 6;
  int lane = threadIdx.x & 63;
  int o = lane & 7, g = lane >> 3;   // g == co
  float wp[8];
  #pragma unroll
  for (int j = 0; j < 8; j++) wp[j] = Wp[(g * 8 + j) * 8 + o];
  float bpv = bp[o];

  int nodeA = blockIdx.x * 8 + w * 2;
  int nodeB = nodeA + 1;
  if (nodeA >= n) return;
  bool vB = nodeB < n;

  int begA = rowptr[nodeA], degA = rowptr[nodeA + 1] - begA;
  float dnA = darr[nodeA];
  int begB = 0, degB = 0; float dnB = 0.f;
  if (vB){ begB = rowptr[nodeB]; degB = rowptr[nodeB + 1] - begB; dnB = darr[nodeB]; }
  bool fastA = degA <= 128;
  bool fastB = vB && degB <= 128;

  if (fastA){
    int c0, c1; float a0, a1;
    agg_softmax(sarr, col, begA, degA, dnA, lane, c0, c1, a0, a1);
    if (lane < degA)      stash[w][0][lane]      = make_int2(c0, __float_as_int(a0));
    if (lane + 64 < degA) stash[w][0][lane + 64] = make_int2(c1, __float_as_int(a1));
  }
  if (fastB){
    int c0, c1; float a0, a1;
    agg_softmax(sarr, col, begB, degB, dnB, lane, c0, c1, a0, a1);
    if (lane < degB)      stash[w][1][lane]      = make_int2(c0, __float_as_int(a0));
    if (lane + 64 < degB) stash[w][1][lane + 64] = make_int2(c1, __float_as_int(a1));
  }

  const float4 b0 = *(const float4*)(bias + g * 8);
  const float4 b1 = *(const float4*)(bias + g * 8 + 4);

  if (fastA && fastB){
    float4 A0, A1, B0, B1;
    agg_gather16x2(h16, degA, degB, lane, stash[w][0], stash[w][1], A0, A1, B0, B1);
    float r0 = fmaxf(A0.x + b0.x, 0.f), r1 = fmaxf(A0.y + b0.y, 0.f);
    float r2 = fmaxf(A0.z + b0.z, 0.f), r3 = fmaxf(A0.w + b0.w, 0.f);
    float r4 = fmaxf(A1.x + b1.x, 0.f), r5 = fmaxf(A1.y + b1.y, 0.f);
    float r6 = fmaxf(A1.z + b1.z, 0.f), r7 = fmaxf(A1.w + b1.w, 0.f);
    float poA = r0*wp[0] + r1*wp[1] + r2*wp[2] + r3*wp[3]
              + r4*wp[4] + r5*wp[5] + r6*wp[6] + r7*wp[7];
    r0 = fmaxf(B0.x + b0.x, 0.f); r1 = fmaxf(B0.y + b0.y, 0.f);
    r2 = fmaxf(B0.z + b0.z, 0.f); r3 = fmaxf(B0.w + b0.w, 0.f);
    r4 = fmaxf(B1.x + b1.x, 0.f); r5 = fmaxf(B1.y + b1.y, 0.f);
    r6 = fmaxf(B1.z + b1.z, 0.f); r7 = fmaxf(B1.w + b1.w, 0.f);
    float poB = r0*wp[0] + r1*wp[1] + r2*wp[2] + r3*wp[3]
              + r4*wp[4] + r5*wp[5] + r6*wp[6] + r7*wp[7];
    poA += __shfl_xor(poA, 8);  poB += __shfl_xor(poB, 8);
    poA += __shfl_xor(poA, 16); poB += __shfl_xor(poB, 16);
    poA += __shfl_xor(poA, 32); poB += __shfl_xor(poB, 32);
    if (lane < 8){
      out[(size_t)nodeA * 8 + lane] = poA + bpv;
      out[(size_t)nodeB * 8 + lane] = poB + bpv;
    }
  } else {
    if (fastA){
      float4 A0, A1;
      agg_gather16(h16, degA, lane, stash[w][0], A0, A1);
      float r0 = fmaxf(A0.x + b0.x, 0.f), r1 = fmaxf(A0.y + b0.y, 0.f);
      float r2 = fmaxf(A0.z + b0.z, 0.f), r3 = fmaxf(A0.w + b0.w, 0.f);
      float r4 = fmaxf(A1.x + b1.x, 0.f), r5 = fmaxf(A1.y + b1.y, 0.f);
      float r6 = fmaxf(A1.z + b1.z, 0.f), r7 = fmaxf(A1.w + b1.w, 0.f);
      float po = r0*wp[0] + r1*wp[1] + r2*wp[2] + r3*wp[3]
               + r4*wp[4] + r5*wp[5] + r6*wp[6] + r7*wp[7];
      po += __shfl_xor(po, 8); po += __shfl_xor(po, 16); po += __shfl_xor(po, 32);
      if (lane < 8) out[(size_t)nodeA * 8 + lane] = po + bpv;
    } else {
      float acc = agg_slow(h16, sarr, col, begA, degA, dnA, lane);
      float r = fmaxf(acc + bias[lane], 0.f);
      float po = 0.f;
      #pragma unroll
      for (int j = 0; j < 8; j++) po += __shfl(r, g * 8 + j) * wp[j];
      po += __shfl_xor(po, 8); po += __shfl_xor(po, 16); po += __shfl_xor(po, 32);
      if (lane < 8) out[(size_t)nodeA * 8 + lane] = po + bpv;
    }
    if (vB){
      if (fastB){
        float4 A0, A1;
        agg_gather16(h16, degB, lane, stash[w][1], A0, A1);
        float r0 = fmaxf(A0.x + b0.x, 0.f), r1 = fmaxf(A0.y + b0.y, 0.f);
        float r2 = fmaxf(A0.z + b0.z, 0.f), r3 = fmaxf(A0.w + b0.w, 0.f);
        float r4 = fmaxf(A1.x + b1.x, 0.f), r5 = fmaxf(A1.y + b1.y, 0.f);
        float r6 = fmaxf(A1.z + b1.z, 0.f), r7 = fmaxf(A1.w + b1.w, 0.f);
        float po = r0*wp[0] + r1*wp[1] + r2*wp[2] + r3*wp[3]
                 + r4*wp[4] + r5*wp[5] + r6*wp[6] + r7*wp[7];
        po += __shfl_xor(po, 8); po += __shfl_xor(po, 16); po += __shfl_xor(po, 32);
        if (lane < 8) out[(size_t)nodeB * 8 + lane] = po + bpv;
      } else {
        float acc = agg_slow(h16, sarr, col, begB, degB, dnB, lane);
        float r = fmaxf(acc + bias[lane], 0.f);
        float po = 0.f;
        #pragma unroll
        for (int j = 0; j < 8; j++) po += __shfl(r, g * 8 + j) * wp[j];
        po += __shfl_xor(po, 8); po += __shfl_xor(po, 16); po += __shfl_xor(po, 32);
        if (lane < 8) out[(size_t)nodeB * 8 + lane] = po + bpv;
      }
    }
  }
}

// ---------------- launch ----------------

extern "C" void kernel_launch(void* const* d_in, const int* in_sizes, int n_in,
                              void* d_out, int out_size, void* d_ws, size_t ws_size,
                              hipStream_t stream) {
  const float* x   = (const float*)d_in[0];
  const int*   ei  = (const int*)  d_in[1];
  const float* W1  = (const float*)d_in[2];
  const float* as1 = (const float*)d_in[3];
  const float* ad1 = (const float*)d_in[4];
  const float* b1  = (const float*)d_in[5];
  const float* W2  = (const float*)d_in[6];
  const float* as2 = (const float*)d_in[7];
  const float* ad2 = (const float*)d_in[8];
  const float* b2  = (const float*)d_in[9];
  const float* Wp  = (const float*)d_in[10];
  const float* bp  = (const float*)d_in[11];
  float* out = (float*)d_out;

  int N = in_sizes[0] / 16;
  int E = in_sizes[1] / 2;
  int TOT = E + N;
  int NB = (N + 255) >> 8;            // buckets of 256 dst nodes
  int T  = (TOT + TILE - 1) / TILE;   // edge tiles

  char* p = (char*)d_ws;
  auto alloc = [&](size_t bytes) -> char* {
    char* r = p; p += (bytes + 255) & ~(size_t)255; return r;
  };
  __half* h16   = (__half*)alloc((size_t)N * 64 * 2);
  float* buf    = (float*)alloc((size_t)N * 64 * 4);
  float* sA     = (float*)alloc((size_t)N * 4);
  float* dA     = (float*)alloc((size_t)N * 4);
  int*   rowptr = (int*)  alloc((size_t)(N + 1) * 4);
  int*   col    = (int*)  alloc((size_t)TOT * 4);
  int*   Bstart = (int*)  alloc((size_t)(NB + 1) * 4);
  int*   Btot   = (int*)  alloc((size_t)(NB + 1) * 4);

  // scratch aliased onto h16/buf (both first written AFTER the CSR build)
  unsigned int* tmp  = (unsigned int*)h16;         // TOT u32 <= N*64*2
  int*          Cmat = (int*)buf;                  // NB*T ints
  int*          Omat = Cmat + (size_t)NB * T;      // NB*T ints

  const int tb = 256;

  // CSR build (dst-grouped) — bucket pipeline
  (void)hipMemsetAsync(Btot, 0, (size_t)(NB + 1) * 4, stream);
  k_bcount<<<T, tb, 0, stream>>>(ei, Cmat, Btot, E, TOT, NB, T);
  k_bstart<<<1, 512, 0, stream>>>(Btot, Bstart, rowptr, NB, TOT, N);
  k_bcolscan<<<(NB + 3) / 4, tb, 0, stream>>>(Cmat, Bstart, Omat, NB, T);
  k_bscatter<<<T, tb, 0, stream>>>(ei, Omat, tmp, E, TOT, NB, T);
  k_bfinal<<<NB, tb, 0, stream>>>(tmp, Bstart, rowptr, col, N);

  // layer 1
  k_dense16<<<(2 * N + tb - 1) / tb, tb, 0, stream>>>(x, W1, as1, ad1, h16, sA, dA, N);
  k_agg1<<<(N + 7) / 8, 256, 0, stream>>>(h16, sA, dA, rowptr, col, b1, buf, N);
  // layer 2 (+ fused policy head)
  k_dense64<<<(2 * N + tb - 1) / tb, tb, 0, stream>>>(buf, W2, as2, ad2, h16, sA, dA, N);
  k_agg2<<<(N + 7) / 8, 256, 0, stream>>>(h16, sA, dA, rowptr, col, b2, Wp, bp, out, N);
}